// Round 6
// baseline (7691.245 us; speedup 1.0000x reference)
//
#include <hip/hip_runtime.h>

// Problem constants
#define NB   128
#define LSEQ 2048
#define HID  512
#define EMB  256
#define KD   768
// Structure: batch rows are INDEPENDENT. 8 n-groups x 16 n; each group split
// over 32 h-blocks x 16 h. 256 blocks, 512 threads = 8 waves, K split 96/wave.
#define NGRP  8
#define NPG   16
#define HBLK  32
#define HPB   16
#define NWG   256
#define NTHR  512
#define RING  4
#define KSL   96
#define FPAD  64   // ints per flag slot (256 B): one producer per cache line
// Sentinel: 4x f16 0xFFFF (NaN). h = O*tanh(C) is always finite, and f16
// conversion of a finite float can never produce 0xFFFF, so valid data never
// aliases the sentinel. Each 8B word is written by ONE store -> no tearing.
#define SENT 0xFFFFFFFFFFFFFFFFull

// Dynamic LDS layout:
//   red:   2 x [8][4][16][20] f32  (double-buffered reduction)  = 81920 B
//   stage: 2 x [16 n][256 f16]     (double-buffered E tiles)    = 16384 B
#define RED_FLOATS 10240
#define RED_BYTES  (RED_FLOATS * 4)
#define STG_BASE   (2 * RED_BYTES)
#define STG_BYTES  8192
#define DSMEM      (STG_BASE + 2 * STG_BYTES)   // 98304 B -> 1 block/CU

#define AT_RLX __ATOMIC_RELAXED
#define SCOPE  __HIP_MEMORY_SCOPE_AGENT

typedef unsigned long long ull;
typedef _Float16 f16;
typedef f16   f16x8 __attribute__((ext_vector_type(8)));
typedef float f32x4 __attribute__((ext_vector_type(4)));

__device__ __forceinline__ float sigf(float x) { return 1.0f / (1.0f + __expf(-x)); }
__device__ __forceinline__ float tanhfast(float x) { return fmaf(-2.0f, 1.0f / (1.0f + __expf(2.0f * x)), 1.0f); }

// Stage address: row n (512 B), byte col c2, XOR-swizzled so consumers reading
// a fixed col across 16 n rows spread over 8 bank-groups (<=2-way, free).
__device__ __forceinline__ int stg_off(int buf, int n, int c2) {
    return STG_BASE + buf * STG_BYTES + n * 512 + (c2 ^ ((n & 7) << 4));
}

// Drain this wave's vmem (stores ack'd at LLC) then lane0 publishes the flag.
__device__ __forceinline__ void publish_flag(int* fl, int val, int is_l0) {
    __builtin_amdgcn_s_waitcnt(0);
    if (is_l0) __hip_atomic_store(fl, val, AT_RLX, SCOPE);
}

__global__ void __launch_bounds__(NTHR, 2)
lstm_pers(const int* __restrict__ X, const float* __restrict__ E,
          const float* __restrict__ Ww, const float* __restrict__ Wb,
          float* __restrict__ out, float* __restrict__ ws)
{
    extern __shared__ char dlds[];

    const int tid  = threadIdx.x;
    const int bid  = blockIdx.x;
    const int ng   = bid & (NGRP - 1);     // n-group (bid&7 -> XCD-local heuristic)
    const int hb   = bid >> 3;             // h-block 0..31
    const int w    = tid >> 6;             // wave 0..7
    const int lane = tid & 63;
    const int quad = lane >> 4;
    const int m16  = lane & 15;
    const int ks   = w * KSL;              // this wave's K base (96 wide)
    const int koff = quad * 8;

    // Hbuf layout: [ng][slot][hb][n=16][h=16] fp16 -> each producer owns a
    // contiguous 512 B block (single writer; no false sharing).
    f16* Hbuf  = (f16*)ws;
    // flags: [ng][hb], 256 B apart. Used ONLY for the t==1 rendezvous; reset
    // to 0 at t==LSEQ-1 so the rendezvous is sound across dispatches.
    int* flags = (int*)((char*)ws + (size_t)NGRP * RING * HBLK * NPG * HPB * 2);

    // ---- init: W fragments -> VGPRs (fp16), persistent for whole kernel ----
    // A-frag layout (16x16x32): lane holds A[m=lane&15][k=quad*8+j], j=0..7.
    f16x8 wf[4][3];
    #pragma unroll
    for (int g = 0; g < 4; ++g) {
        #pragma unroll
        for (int ti = 0; ti < 3; ++ti) {
            const float* wp = Ww + (size_t)(g * HID + hb * HPB + m16) * KD
                                 + (ks + ti * 32 + koff);
            f16x8 v;
            #pragma unroll
            for (int j = 0; j < 8; ++j) v[j] = (f16)wp[j];
            wf[g][ti] = v;
        }
    }
    // bias + cell state live in wave 7 (the epilogue wave)
    f32x4 bias[4], cst = {0, 0, 0, 0};
    if (w == 7) {
        #pragma unroll
        for (int g = 0; g < 4; ++g)
            bias[g] = *(const f32x4*)(Wb + g * HID + hb * HPB + quad * 4);
        // Sentinel-fill own 512B block in slots 2 and 3 (first read at t=2,3).
        // Drained by epilogue-0's publish_flag before any consumer can pass
        // the t==1 rendezvous. Slot 1 is covered by the rendezvous itself;
        // slot 0's sentinel is written at epilogue 1 (ordering chain: it is
        // drained by epilogue-2's waitcnt, which precedes the H(3) data any
        // consumer must see before reaching its t=4 poll of slot 0).
        #pragma unroll
        for (int s = 2; s <= 3; ++s) {
            ull* z = (ull*)(Hbuf + ((size_t)(ng * RING + s) * HBLK + hb)
                            * (NPG * HPB) + lane * 4);
            __hip_atomic_store(z, SENT, AT_RLX, SCOPE);
        }
    }

    // ---- E-stage prologue: waves 0-3 stage E(0) into stage[0] ----
    // Loader lane: n = m16, pieces kcA = w*8+quad and kcA+4 (8 f16 = 16 B each).
    const int xrow = (ng * NPG + m16) * LSEQ;
    const int kcA  = w * 8 + quad;
    int xN = 0;
    if (w < 4) {
        int x0 = X[xrow + 0];
        xN = X[xrow + 1];
        const float* ebp = E + (size_t)x0 * EMB;
        #pragma unroll
        for (int p = 0; p < 2; ++p) {
            int kc = kcA + 4 * p;
            f32x4 e0 = *(const f32x4*)(ebp + kc * 8);
            f32x4 e1 = *(const f32x4*)(ebp + kc * 8 + 4);
            f16x8 v;
            #pragma unroll
            for (int j = 0; j < 4; ++j) { v[j] = (f16)e0[j]; v[4 + j] = (f16)e1[j]; }
            *(f16x8*)(dlds + stg_off(0, m16, kc * 16)) = v;
        }
    }
    __syncthreads();                       // init + stage[0] visible

    // wave 6 polls the 32 producer flags once, at t==1.
    const int* fp6 = flags + (size_t)(ng * HBLK + (lane & (HBLK - 1))) * FPAD;
    int* myflag = &flags[(ng * HBLK + hb) * FPAD];
    const int nh = (ks + 64 < HID) ? 3 : ((ks < HID) ? 1 : 0);

    for (int t = 0; t < LSEQ; ++t) {
        // ---- loaders: issue E(t+1) gathers early (latency hides under the
        //      H-poll spin) + X(t+2) prefetch ----
        f32x4 ea0, ea1, eb0, eb1; int xF = 0;
        const bool stg_go = (w < 4) && (t + 1 < LSEQ);
        if (stg_go) {
            const float* ebp = E + (size_t)xN * EMB;
            ea0 = *(const f32x4*)(ebp + kcA * 8);
            ea1 = *(const f32x4*)(ebp + kcA * 8 + 4);
            eb0 = *(const f32x4*)(ebp + (kcA + 4) * 8);
            eb1 = *(const f32x4*)(ebp + (kcA + 4) * 8 + 4);
        }
        if (w < 4) {
            int nidx = (t + 2 < LSEQ) ? t + 2 : LSEQ - 1;
            xF = X[xrow + nidx];
        }

        f16x8 bf[3];
        // ---- consumers: E tiles for THIS step from stage[t&1] (LDS) ----
        if (ks + 64 >= HID) {
            #pragma unroll
            for (int ti = 0; ti < 3; ++ti) {
                int k0 = ks + ti * 32;
                if (k0 >= HID) {
                    int c2 = (k0 - HID + koff) * 2;
                    bf[ti] = *(const f16x8*)(dlds + stg_off(t & 1, m16, c2));
                }
            }
        }
        // ---- one-time rendezvous: all producers published H(1) + init fills.
        //      The conditional barrier gates every wave's slot-1/2/3 access
        //      behind it (sound even on a zeroed/stale workspace). ----
        if (w == 6 && t == 1) {
            while (!__all(__hip_atomic_load(fp6, AT_RLX, SCOPE) >= 1))
                __builtin_amdgcn_s_sleep(1);
        }
        if (t == 1) __syncthreads();

        // ---- H tiles: sentinel-validated self-service (no flags, no drain) ----
        if (t == 0) {
            f16x8 z;
            #pragma unroll
            for (int j = 0; j < 8; ++j) z[j] = (f16)0.0f;
            for (int ti = 0; ti < nh; ++ti) bf[ti] = z;
        } else if (nh == 3) {
            const f16* Hc = Hbuf + (size_t)(ng * RING + (t & 3)) * HBLK * (NPG * HPB);
            int ka = ks + koff, kb = ka + 32, kc = kb + 32;
            const ull* h0 = (const ull*)(Hc + (size_t)(ka >> 4) * (NPG * HPB) + m16 * HPB + (ka & 15));
            const ull* h1 = (const ull*)(Hc + (size_t)(kb >> 4) * (NPG * HPB) + m16 * HPB + (kb & 15));
            const ull* h2 = (const ull*)(Hc + (size_t)(kc >> 4) * (NPG * HPB) + m16 * HPB + (kc & 15));
            ull u0, u1, u2, u3, u4, u5;
            for (;;) {
                u0 = __hip_atomic_load(h0,     AT_RLX, SCOPE);
                u1 = __hip_atomic_load(h0 + 1, AT_RLX, SCOPE);
                u2 = __hip_atomic_load(h1,     AT_RLX, SCOPE);
                u3 = __hip_atomic_load(h1 + 1, AT_RLX, SCOPE);
                u4 = __hip_atomic_load(h2,     AT_RLX, SCOPE);
                u5 = __hip_atomic_load(h2 + 1, AT_RLX, SCOPE);
                bool ok = (u0 != SENT) & (u1 != SENT) & (u2 != SENT)
                        & (u3 != SENT) & (u4 != SENT) & (u5 != SENT);
                if (__all(ok)) break;
                __builtin_amdgcn_s_sleep(1);
            }
            union { ull u[2]; f16x8 v; } c;
            c.u[0] = u0; c.u[1] = u1; bf[0] = c.v;
            c.u[0] = u2; c.u[1] = u3; bf[1] = c.v;
            c.u[0] = u4; c.u[1] = u5; bf[2] = c.v;
        } else if (nh == 1) {
            const f16* Hc = Hbuf + (size_t)(ng * RING + (t & 3)) * HBLK * (NPG * HPB);
            int ka = ks + koff;
            const ull* h0 = (const ull*)(Hc + (size_t)(ka >> 4) * (NPG * HPB) + m16 * HPB + (ka & 15));
            ull u0, u1;
            for (;;) {
                u0 = __hip_atomic_load(h0,     AT_RLX, SCOPE);
                u1 = __hip_atomic_load(h0 + 1, AT_RLX, SCOPE);
                if (__all((u0 != SENT) & (u1 != SENT))) break;
                __builtin_amdgcn_s_sleep(1);
            }
            union { ull u[2]; f16x8 v; } c;
            c.u[0] = u0; c.u[1] = u1; bf[0] = c.v;
        }
        // ---- MFMA: 4 gates x 3 K-tiles ----
        f32x4 acc[4] = {{0,0,0,0},{0,0,0,0},{0,0,0,0},{0,0,0,0}};
        #pragma unroll
        for (int ti = 0; ti < 3; ++ti)
            #pragma unroll
            for (int g = 0; g < 4; ++g)
                acc[g] = __builtin_amdgcn_mfma_f32_16x16x32_f16(wf[g][ti], bf[ti], acc[g], 0, 0, 0);

        // ---- deposit partials into red[t&1] (conflict-free padded layout) ----
        float* redp = (float*)dlds + (size_t)(t & 1) * RED_FLOATS;
        #pragma unroll
        for (int g = 0; g < 4; ++g)
            *(f32x4*)&redp[(((w * 4 + g) * 16 + m16) * 20) + quad * 4] = acc[g];

        // ---- loaders: convert + stage E(t+1) into stage[(t+1)&1] ----
        if (stg_go) {
            f16x8 va, vb;
            #pragma unroll
            for (int j = 0; j < 4; ++j) {
                va[j] = (f16)ea0[j]; va[4 + j] = (f16)ea1[j];
                vb[j] = (f16)eb0[j]; vb[4 + j] = (f16)eb1[j];
            }
            *(f16x8*)(dlds + stg_off((t + 1) & 1, m16, kcA * 16))       = va;
            *(f16x8*)(dlds + stg_off((t + 1) & 1, m16, (kcA + 4) * 16)) = vb;
        }
        if (w < 4) xN = xF;
        __syncthreads();               // bar B: partials + next-stage visible

        if (w == 7) {
            // Epilogue overlaps with peers' step-(t+1) polls (no bar A).
            f32x4 G[4];
            #pragma unroll
            for (int g = 0; g < 4; ++g) {
                f32x4 s = bias[g];
                #pragma unroll
                for (int wv = 0; wv < 8; ++wv) {
                    f32x4 r = *(const f32x4*)&redp[(((wv * 4 + g) * 16 + m16) * 20) + quad * 4];
                    s.x += r.x; s.y += r.y; s.z += r.z; s.w += r.w;
                }
                G[g] = s;
            }
            union { f16 h[4]; ull u; } pk;
            f32x4 ov;
            #pragma unroll
            for (int s = 0; s < 4; ++s) {
                float F = sigf(G[0][s]);
                float I = sigf(G[1][s]);
                float O = sigf(G[2][s]);
                float T = tanhfast(G[3][s]);
                cst[s] = fmaf(F, cst[s], I * T);
                float hn = O * tanhfast(cst[s]);
                pk.h[s] = (f16)hn;
                ov[s] = hn;
            }
            if (t < LSEQ - 1) {
                // Drain: the sentinel for slot (t+1)&3 (issued at epilogue
                // t-2, one full step old -> free) must land before data.
                // Wave 7 has no loads in steady state, so this is cheap.
                __builtin_amdgcn_s_waitcnt(0);
                f16* Hw = Hbuf + ((size_t)(ng * RING + ((t + 1) & 3)) * HBLK + hb)
                                 * (NPG * HPB);
                __hip_atomic_store((ull*)(Hw + m16 * HPB + quad * 4), pk.u,
                                   AT_RLX, SCOPE);
                if (t == 0) {
                    // one-time: drain H(1) + init sentinels, then flag=1
                    publish_flag(myflag, 1, lane == 0);
                } else if (t + 3 < LSEQ) {
                    // Sentinel-fill slot (t+3)&3 for its next incarnation.
                    // Readers of its previous data are provably done (they
                    // passed bar B(t-1) before H(t) could exist).
                    f16* Hs = Hbuf + ((size_t)(ng * RING + ((t + 3) & 3)) * HBLK + hb)
                                     * (NPG * HPB);
                    __hip_atomic_store((ull*)(Hs + m16 * HPB + quad * 4), SENT,
                                       AT_RLX, SCOPE);
                }
            } else {
                *(f32x4*)(out + (size_t)(ng * NPG + m16) * HID + hb * HPB + quad * 4) = ov;
                // Reset flag so the next dispatch's t==1 rendezvous is sound.
                if (lane == 0) __hip_atomic_store(myflag, 0, AT_RLX, SCOPE);
            }
        }
        // Slot safety (RING=4): producer reaches epilogue t only after seeing
        // all of H(t), i.e. every block passed bar B(t-1), i.e. all reads of
        // H(t-1) and earlier are complete.
        // red dbuf safety: deposits at t+1 target red[(t+1)&1]; red[t&1] is
        // redeposited only after bar B(t+1), which wave 7 reaches after its
        // epilogue-t reads. Stage dbuf safety: writes to stage[(t+1)&1] land
        // before bar B(t); reads happen after it.
    }
}

extern "C" void kernel_launch(void* const* d_in, const int* in_sizes, int n_in,
                              void* d_out, int out_size, void* d_ws, size_t ws_size,
                              hipStream_t stream) {
    const int*   X   = (const int*)d_in[0];
    const float* E   = (const float*)d_in[1];
    const float* Ww  = (const float*)d_in[2];
    const float* Wb  = (const float*)d_in[3];
    float*       out = (float*)d_out;
    float*       ws  = (float*)d_ws;

    static int attr_done = 0;
    if (!attr_done) {
        (void)hipFuncSetAttribute((const void*)lstm_pers,
                                  hipFuncAttributeMaxDynamicSharedMemorySize,
                                  DSMEM);
        attr_done = 1;
    }

    void* args[] = { (void*)&X, (void*)&E, (void*)&Ww, (void*)&Wb,
                     (void*)&out, (void*)&ws };
    hipError_t e = hipLaunchCooperativeKernel((const void*)lstm_pers, dim3(NWG), dim3(NTHR),
                                              args, DSMEM, stream);
    if (e != hipSuccess) {
        // 256 blocks, 96KB dynamic LDS -> 1 block/CU co-resident on 256 CUs.
        hipLaunchKernelGGL(lstm_pers, dim3(NWG), dim3(NTHR), DSMEM, stream,
                           X, E, Ww, Wb, out, ws);
    }
}

// Round 7
// 6786.562 us; speedup vs baseline: 1.1333x; 1.1333x over previous
//
#include <hip/hip_runtime.h>

// Problem constants
#define NB   128
#define LSEQ 2048
#define HID  512
#define EMB  256
#define KD   768
// Structure: batch rows are INDEPENDENT. 8 n-groups x 16 n; each group split
// over 32 h-blocks x 16 h. 256 blocks, 512 threads = 8 waves, K split 96/wave.
#define NGRP  8
#define NPG   16
#define HBLK  32
#define HPB   16
#define NWG   256
#define NTHR  512
#define RING  4
#define KSL   96
#define FPAD  64   // ints per flag slot (256 B): one producer per cache line
// Sentinel: f16 0xFFFF (NaN). h = O*tanh(C) is always finite, and f16
// conversion of a finite float can never produce 0xFFFF, so valid data never
// aliases the sentinel. Stores are 4 B per lane (one writer per 4 B), so
// validation is PER-4B; 8 B loads may tear across halves, which is benign.
#define SENT   0xFFFFFFFFFFFFFFFFull
#define SENT4  0xFFFFFFFFu

// Dynamic LDS: red = 2 x [8][4][16][20] f32 (double-buffered reduction).
#define RED_FLOATS 10240
#define DSMEM      (2 * RED_FLOATS * 4)   // 81920 B -> 1 block/CU

#define AT_RLX __ATOMIC_RELAXED
#define SCOPE  __HIP_MEMORY_SCOPE_AGENT

typedef unsigned long long ull;
typedef unsigned int uint;
typedef _Float16 f16;
typedef f16   f16x8 __attribute__((ext_vector_type(8)));
typedef float f32x4 __attribute__((ext_vector_type(4)));

__device__ __forceinline__ float sigf(float x) { return 1.0f / (1.0f + __expf(-x)); }
__device__ __forceinline__ float tanhfast(float x) { return fmaf(-2.0f, 1.0f / (1.0f + __expf(2.0f * x)), 1.0f); }

// Per-4B sentinel validation of an 8B word.
__device__ __forceinline__ bool ok8(ull u) {
    return ((uint)u != SENT4) && ((uint)(u >> 32) != SENT4);
}

// Drain this wave's vmem (stores ack'd at LLC) then lane0 publishes the flag.
__device__ __forceinline__ void publish_flag(int* fl, int val, int is_l0) {
    __builtin_amdgcn_s_waitcnt(0);
    if (is_l0) __hip_atomic_store(fl, val, AT_RLX, SCOPE);
}

__global__ void __launch_bounds__(NTHR, 2)
lstm_pers(const int* __restrict__ X, const float* __restrict__ E,
          const float* __restrict__ Ww, const float* __restrict__ Wb,
          float* __restrict__ out, float* __restrict__ ws)
{
    extern __shared__ char dlds[];

    const int tid  = threadIdx.x;
    const int bid  = blockIdx.x;
    const int ng   = bid & (NGRP - 1);     // n-group (bid&7 -> XCD-local heuristic)
    const int hb   = bid >> 3;             // h-block 0..31
    const int w    = tid >> 6;             // wave 0..7
    const int lane = tid & 63;
    const int quad = lane >> 4;
    const int m16  = lane & 15;
    const int ks   = w * KSL;              // this wave's K base (96 wide)
    const int koff = quad * 8;

    // Hbuf layout: [ng][slot][hb][n=16][h=16] fp16 -> each producer block owns
    // a contiguous 512 B block (written only by its waves 6/7; no false
    // sharing across blocks).
    f16* Hbuf  = (f16*)ws;
    // flags: [ng][hb], 256 B apart. Words [0] (wave 7) and [8] (wave 6) are
    // used ONLY for the t==1 rendezvous; reset at t==LSEQ-1.
    int* flags = (int*)((char*)ws + (size_t)NGRP * RING * HBLK * NPG * HPB * 2);

    // ---- init: W fragments -> VGPRs (fp16), persistent for whole kernel ----
    // A-frag layout (16x16x32): lane holds A[m=lane&15][k=quad*8+j], j=0..7.
    f16x8 wf[4][3];
    #pragma unroll
    for (int g = 0; g < 4; ++g) {
        #pragma unroll
        for (int ti = 0; ti < 3; ++ti) {
            const float* wp = Ww + (size_t)(g * HID + hb * HPB + m16) * KD
                                 + (ks + ti * 32 + koff);
            f16x8 v;
            #pragma unroll
            for (int j = 0; j < 8; ++j) v[j] = (f16)wp[j];
            wf[g][ti] = v;
        }
    }

    // ---- epilogue waves 6,7: each owns an h-half (2 h per lane) ----
    const int half = w - 6;                   // 0 (wave 6) or 1 (wave 7)
    const int hoff = half * 8 + quad * 2;     // this lane's 2 h within the 16
    float2 bias2[4];
    float  cst0 = 0.0f, cst1 = 0.0f;
    if (w >= 6) {
        #pragma unroll
        for (int g = 0; g < 4; ++g) {
            const float* bp = Wb + g * HID + hb * HPB + hoff;
            bias2[g] = make_float2(bp[0], bp[1]);
        }
        // Sentinel-fill own half of own 512B block in slots 2,3 (first read at
        // t=2,3). Drained by this wave's epilogue-0 publish_flag before any
        // consumer can pass the t==1 rendezvous. Slot 1 is covered by the
        // rendezvous itself; slot 0's sentinel is written at epilogue 1.
        #pragma unroll
        for (int s = 2; s <= 3; ++s) {
            uint* z = (uint*)(Hbuf + ((size_t)(ng * RING + s) * HBLK + hb)
                              * (NPG * HPB) + m16 * HPB + hoff);
            __hip_atomic_store(z, SENT4, AT_RLX, SCOPE);
        }
    }
    __syncthreads();

    // wave 6 polls the 32 producers' dual flag words once, at t==1.
    const int* fp6 = flags + (size_t)(ng * HBLK + (lane & (HBLK - 1))) * FPAD;
    int* myflag = &flags[(ng * HBLK + hb) * FPAD];
    const int nh = (ks + 64 < HID) ? 3 : ((ks < HID) ? 1 : 0);

    for (int t = 0; t < LSEQ; ++t) {
        f16x8 bf[3];
        // ---- E tiles first (plain cached reads, in flight during poll) ----
        if (ks + 64 >= HID) {                    // wave has >=1 E tile
            int xi = X[(ng * NPG + m16) * LSEQ + t];
            const float* eb = E + (size_t)xi * EMB;
            #pragma unroll
            for (int ti = 0; ti < 3; ++ti) {
                int k0 = ks + ti * 32;
                if (k0 >= HID) {
                    const float* ep = eb + (k0 - HID) + koff;
                    f32x4 e0 = *(const f32x4*)(ep);
                    f32x4 e1 = *(const f32x4*)(ep + 4);
                    f16x8 v;
                    #pragma unroll
                    for (int j = 0; j < 4; ++j) { v[j] = (f16)e0[j]; v[4 + j] = (f16)e1[j]; }
                    bf[ti] = v;
                }
            }
        }
        // ---- one-time rendezvous: all producers' BOTH epilogue waves
        //      published H(1) + their init sentinels ----
        if (w == 6 && t == 1) {
            for (;;) {
                int f0 = __hip_atomic_load(fp6,     AT_RLX, SCOPE);
                int f1 = __hip_atomic_load(fp6 + 8, AT_RLX, SCOPE);
                if (__all((f0 >= 1) && (f1 >= 1))) break;
                __builtin_amdgcn_s_sleep(1);
            }
        }
        if (t == 1) __syncthreads();

        // ---- H tiles: sentinel-validated self-service (no flags, no drain) ----
        if (t == 0) {
            f16x8 z;
            #pragma unroll
            for (int j = 0; j < 8; ++j) z[j] = (f16)0.0f;
            for (int ti = 0; ti < nh; ++ti) bf[ti] = z;
        } else if (nh == 3) {
            const f16* Hc = Hbuf + (size_t)(ng * RING + (t & 3)) * HBLK * (NPG * HPB);
            int ka = ks + koff, kb = ka + 32, kc = kb + 32;
            const ull* h0 = (const ull*)(Hc + (size_t)(ka >> 4) * (NPG * HPB) + m16 * HPB + (ka & 15));
            const ull* h1 = (const ull*)(Hc + (size_t)(kb >> 4) * (NPG * HPB) + m16 * HPB + (kb & 15));
            const ull* h2 = (const ull*)(Hc + (size_t)(kc >> 4) * (NPG * HPB) + m16 * HPB + (kc & 15));
            ull u0, u1, u2, u3, u4, u5;
            for (;;) {
                u0 = __hip_atomic_load(h0,     AT_RLX, SCOPE);
                u1 = __hip_atomic_load(h0 + 1, AT_RLX, SCOPE);
                u2 = __hip_atomic_load(h1,     AT_RLX, SCOPE);
                u3 = __hip_atomic_load(h1 + 1, AT_RLX, SCOPE);
                u4 = __hip_atomic_load(h2,     AT_RLX, SCOPE);
                u5 = __hip_atomic_load(h2 + 1, AT_RLX, SCOPE);
                bool ok = ok8(u0) & ok8(u1) & ok8(u2)
                        & ok8(u3) & ok8(u4) & ok8(u5);
                if (__all(ok)) break;
                __builtin_amdgcn_s_sleep(1);
            }
            union { ull u[2]; f16x8 v; } c;
            c.u[0] = u0; c.u[1] = u1; bf[0] = c.v;
            c.u[0] = u2; c.u[1] = u3; bf[1] = c.v;
            c.u[0] = u4; c.u[1] = u5; bf[2] = c.v;
        } else if (nh == 1) {
            const f16* Hc = Hbuf + (size_t)(ng * RING + (t & 3)) * HBLK * (NPG * HPB);
            int ka = ks + koff;
            const ull* h0 = (const ull*)(Hc + (size_t)(ka >> 4) * (NPG * HPB) + m16 * HPB + (ka & 15));
            ull u0, u1;
            for (;;) {
                u0 = __hip_atomic_load(h0,     AT_RLX, SCOPE);
                u1 = __hip_atomic_load(h0 + 1, AT_RLX, SCOPE);
                if (__all(ok8(u0) & ok8(u1))) break;
                __builtin_amdgcn_s_sleep(1);
            }
            union { ull u[2]; f16x8 v; } c;
            c.u[0] = u0; c.u[1] = u1; bf[0] = c.v;
        }
        // ---- MFMA: 4 gates x 3 K-tiles ----
        f32x4 acc[4] = {{0,0,0,0},{0,0,0,0},{0,0,0,0},{0,0,0,0}};
        #pragma unroll
        for (int ti = 0; ti < 3; ++ti)
            #pragma unroll
            for (int g = 0; g < 4; ++g)
                acc[g] = __builtin_amdgcn_mfma_f32_16x16x32_f16(wf[g][ti], bf[ti], acc[g], 0, 0, 0);

        // ---- deposit partials into red[t&1] (conflict-free padded layout) ----
        float* redp = (float*)dlds + (size_t)(t & 1) * RED_FLOATS;
        #pragma unroll
        for (int g = 0; g < 4; ++g)
            *(f32x4*)&redp[(((w * 4 + g) * 16 + m16) * 20) + quad * 4] = acc[g];
        __syncthreads();               // bar B: all partials visible

        if (w >= 6) {
            // Split epilogue: wave 6 -> h 0..7, wave 7 -> h 8..15 (2 h/lane).
            // Overlaps peers' step-(t+1) polls (no bar A; red is dbuf'd).
            float2 G[4];
            #pragma unroll
            for (int g = 0; g < 4; ++g) {
                float2 s = bias2[g];
                #pragma unroll
                for (int wv = 0; wv < 8; ++wv) {
                    const float* r = &redp[(((wv * 4 + g) * 16 + m16) * 20) + hoff];
                    s.x += r[0]; s.y += r[1];
                }
                G[g] = s;
            }
            float F0 = sigf(G[0].x), F1 = sigf(G[0].y);
            float I0 = sigf(G[1].x), I1 = sigf(G[1].y);
            float O0 = sigf(G[2].x), O1 = sigf(G[2].y);
            float T0 = tanhfast(G[3].x), T1 = tanhfast(G[3].y);
            cst0 = fmaf(F0, cst0, I0 * T0);
            cst1 = fmaf(F1, cst1, I1 * T1);
            float hn0 = O0 * tanhfast(cst0);
            float hn1 = O1 * tanhfast(cst1);
            union { f16 h[2]; uint u; } pk;
            pk.h[0] = (f16)hn0; pk.h[1] = (f16)hn1;

            if (t < LSEQ - 1) {
                // Drain: the sentinel for slot (t+1)&3 (issued at this wave's
                // epilogue t-2, one full step old -> free) must land before
                // data overwrites it.
                __builtin_amdgcn_s_waitcnt(0);
                f16* Hw = Hbuf + ((size_t)(ng * RING + ((t + 1) & 3)) * HBLK + hb)
                                 * (NPG * HPB);
                __hip_atomic_store((uint*)(Hw + m16 * HPB + hoff), pk.u,
                                   AT_RLX, SCOPE);
                if (t == 0) {
                    // one-time: drain H(1) half + own init sentinels, then flag
                    publish_flag(myflag + half * 8, 1, lane == 0);
                } else if (t + 3 < LSEQ) {
                    // Sentinel-fill own half of slot (t+3)&3 for its next
                    // incarnation. Readers of its previous data are provably
                    // done (they passed bar B(t-1) before H(t) could exist).
                    f16* Hs = Hbuf + ((size_t)(ng * RING + ((t + 3) & 3)) * HBLK + hb)
                                     * (NPG * HPB);
                    __hip_atomic_store((uint*)(Hs + m16 * HPB + hoff), SENT4,
                                       AT_RLX, SCOPE);
                }
            } else {
                float* op = out + (size_t)(ng * NPG + m16) * HID + hb * HPB + hoff;
                op[0] = hn0; op[1] = hn1;
                // Reset own flag word so the next dispatch's rendezvous is sound.
                if (lane == 0)
                    __hip_atomic_store(myflag + half * 8, 0, AT_RLX, SCOPE);
            }
        }
        // Slot safety (RING=4): producers reach epilogue t only after seeing
        // all of H(t), i.e. every block passed bar B(t-1), i.e. all reads of
        // H(t-1) and earlier are complete.
        // red dbuf safety: deposits at t+1 target red[(t+1)&1]; red[t&1] is
        // redeposited only at t+2, after bar B(t+1), which waves 6/7 reach
        // only after their epilogue-t reads of red[t&1] are done.
    }
}

extern "C" void kernel_launch(void* const* d_in, const int* in_sizes, int n_in,
                              void* d_out, int out_size, void* d_ws, size_t ws_size,
                              hipStream_t stream) {
    const int*   X   = (const int*)d_in[0];
    const float* E   = (const float*)d_in[1];
    const float* Ww  = (const float*)d_in[2];
    const float* Wb  = (const float*)d_in[3];
    float*       out = (float*)d_out;
    float*       ws  = (float*)d_ws;

    static int attr_done = 0;
    if (!attr_done) {
        (void)hipFuncSetAttribute((const void*)lstm_pers,
                                  hipFuncAttributeMaxDynamicSharedMemorySize,
                                  DSMEM);
        attr_done = 1;
    }

    void* args[] = { (void*)&X, (void*)&E, (void*)&Ww, (void*)&Wb,
                     (void*)&out, (void*)&ws };
    hipError_t e = hipLaunchCooperativeKernel((const void*)lstm_pers, dim3(NWG), dim3(NTHR),
                                              args, DSMEM, stream);
    if (e != hipSuccess) {
        // 256 blocks, 80KB dynamic LDS -> 1 block/CU co-resident on 256 CUs.
        hipLaunchKernelGGL(lstm_pers, dim3(NWG), dim3(NTHR), DSMEM, stream,
                           X, E, Ww, Wb, out, ws);
    }
}